// Round 3
// baseline (503.454 us; speedup 1.0000x reference)
//
#include <hip/hip_runtime.h>
#include <math.h>

#define DEVINL __device__ __forceinline__

DEVINL float4 ld4(const float* p) { return *reinterpret_cast<const float4*>(p); }
DEVINL void st4(float* p, const float4 v) { *reinterpret_cast<float4*>(p) = v; }
DEVINL float sigm(float v) { return 1.0f / (1.0f + expf(-v)); }

// ---------------- shapes ----------------
// t1 (8, 64,256,256)  t2 (8,128,128,128)  t3 (8,256,64,64)
// t4 (8,512, 32, 32)  t5 (8,512, 16, 16)
constexpr size_t O1 = 0;
constexpr size_t O2 = O1 + (size_t)8 * 64 * 256 * 256;
constexpr size_t O3 = O2 + (size_t)8 * 128 * 128 * 128;
constexpr size_t O4 = O3 + (size_t)8 * 256 * 64 * 64;
constexpr size_t O5 = O4 + (size_t)8 * 512 * 32 * 32;

// ws layout (float offsets): interleaved (avg,max) float2 maps, then att maps
constexpr size_t MAP1 = 0;
constexpr size_t MAP2 = MAP1 + (size_t)2 * 8 * 256 * 256;
constexpr size_t MAP3 = MAP2 + (size_t)2 * 8 * 128 * 128;
constexpr size_t MAP4 = MAP3 + (size_t)2 * 8 * 64 * 64;
constexpr size_t MAP5 = MAP4 + (size_t)2 * 8 * 32 * 32;
constexpr size_t ATT1 = MAP5 + (size_t)2 * 8 * 16 * 16;
constexpr size_t ATT2 = ATT1 + (size_t)8 * 256 * 256;
constexpr size_t ATT3 = ATT2 + (size_t)8 * 128 * 128;
constexpr size_t ATT4 = ATT3 + (size_t)8 * 64 * 64;
constexpr size_t ATT5 = ATT4 + (size_t)8 * 32 * 32;

// ================= K1: channel mean+max =================
template <int C, int HW>
DEVINL void reduce_simple(const float* __restrict__ in, float* __restrict__ map,
                          unsigned quad) {
  constexpr unsigned QPI = HW / 4;  // quads per image
  unsigned n = quad / QPI;
  unsigned hw0 = (quad & (QPI - 1)) * 4;
  const float* p = in + (size_t)n * ((size_t)C * HW) + hw0;
  float sx = 0.f, sy = 0.f, sz = 0.f, sw = 0.f;
  float mx = -3.402823466e38f, my = mx, mz = mx, mw = mx;
#pragma unroll 8
  for (int c = 0; c < C; ++c) {
    float4 v = ld4(p + (size_t)c * HW);
    sx += v.x; sy += v.y; sz += v.z; sw += v.w;
    mx = fmaxf(mx, v.x); my = fmaxf(my, v.y);
    mz = fmaxf(mz, v.z); mw = fmaxf(mw, v.w);
  }
  constexpr float inv = 1.0f / C;
  float* mp = map + (size_t)(n * (unsigned)HW + hw0) * 2;
  st4(mp,     make_float4(sx * inv, mx, sy * inv, my));
  st4(mp + 4, make_float4(sz * inv, mz, sw * inv, mw));
}

// cooperative version for C=512 tensors: 8 channel-chunks/quad, LDS combine
template <int C, int HW>
DEVINL void reduce_coop(const float* __restrict__ in, float* __restrict__ map,
                        float* s_red, unsigned blockLocal, unsigned tid) {
  constexpr unsigned QPI = HW / 4;
  constexpr int KCH = 8;
  constexpr int CPK = C / KCH;  // 64
  unsigned lane = tid & 31;
  unsigned k = tid >> 5;
  unsigned q = blockLocal * 32 + lane;
  unsigned n = q / QPI;
  unsigned hw0 = (q & (QPI - 1)) * 4;
  const float* p =
      in + (size_t)n * ((size_t)C * HW) + (size_t)(k * CPK) * HW + hw0;
  float sx = 0.f, sy = 0.f, sz = 0.f, sw = 0.f;
  float mx = -3.402823466e38f, my = mx, mz = mx, mw = mx;
#pragma unroll 8
  for (int c = 0; c < CPK; ++c) {
    float4 v = ld4(p + (size_t)c * HW);
    sx += v.x; sy += v.y; sz += v.z; sw += v.w;
    mx = fmaxf(mx, v.x); my = fmaxf(my, v.y);
    mz = fmaxf(mz, v.z); mw = fmaxf(mw, v.w);
  }
  float* slot = s_red + (k * 32 + lane) * 8;
  slot[0] = sx; slot[1] = sy; slot[2] = sz; slot[3] = sw;
  slot[4] = mx; slot[5] = my; slot[6] = mz; slot[7] = mw;
  __syncthreads();
  if (tid < 32) {
    float Sx = 0.f, Sy = 0.f, Sz = 0.f, Sw = 0.f;
    float Mx = -3.402823466e38f, My = Mx, Mz = Mx, Mw = Mx;
#pragma unroll
    for (int j = 0; j < KCH; ++j) {
      const float* sl = s_red + (j * 32 + tid) * 8;
      Sx += sl[0]; Sy += sl[1]; Sz += sl[2]; Sw += sl[3];
      Mx = fmaxf(Mx, sl[4]); My = fmaxf(My, sl[5]);
      Mz = fmaxf(Mz, sl[6]); Mw = fmaxf(Mw, sl[7]);
    }
    unsigned q2 = blockLocal * 32 + tid;
    unsigned n2 = q2 / QPI;
    unsigned hw2 = (q2 & (QPI - 1)) * 4;
    constexpr float inv = 1.0f / C;
    float* mp = map + (size_t)(n2 * (unsigned)HW + hw2) * 2;
    st4(mp,     make_float4(Sx * inv, Mx, Sy * inv, My));
    st4(mp + 4, make_float4(Sz * inv, Mz, Sw * inv, Mw));
  }
}

__global__ __launch_bounds__(256) void k_reduce(
    const float* __restrict__ t1, const float* __restrict__ t2,
    const float* __restrict__ t3, const float* __restrict__ t4,
    const float* __restrict__ t5, float* __restrict__ ws) {
  __shared__ float s_red[8 * 32 * 8];
  unsigned bid = blockIdx.x, tid = threadIdx.x;
  if (bid < 512) {
    reduce_simple<64, 65536>(t1, ws + MAP1, bid * 256 + tid);
  } else if (bid < 640) {
    reduce_simple<128, 16384>(t2, ws + MAP2, (bid - 512) * 256 + tid);
  } else if (bid < 672) {
    reduce_simple<256, 4096>(t3, ws + MAP3, (bid - 640) * 256 + tid);
  } else if (bid < 736) {
    reduce_coop<512, 1024>(t4, ws + MAP4, s_red, bid - 672, tid);
  } else {
    reduce_coop<512, 256>(t5, ws + MAP5, s_red, bid - 736, tid);
  }
}

// ================= K2: dilated 7x7 conv + sigmoid =================
// cross-correlation, dilation 3, pad 9: y(h,w) = sum_{ky,kx} in(h+3ky-9, w+3kx-9)*w(ky,kx)
template <int H, int W>
DEVINL void conv_one(const float* __restrict__ map, float* __restrict__ att,
                     const float* w_s, float bias, unsigned quad) {
  constexpr unsigned QPI = (H * W) / 4;
  unsigned n = quad / QPI;
  unsigned hw0 = (quad & (QPI - 1)) * 4;
  int h = (int)(hw0 / (unsigned)W);
  int w0 = (int)(hw0 & (unsigned)(W - 1));
  const float* base = map + (size_t)n * (2 * H * W);
  float acc[4] = {bias, bias, bias, bias};
#pragma unroll
  for (int ky = 0; ky < 7; ++ky) {
    int y = h + (ky - 3) * 3;
    if ((unsigned)y < (unsigned)H) {
      const float* row = base + (size_t)y * (2 * W);
      float rx[22], ry[22];
#pragma unroll
      for (int j = 0; j < 22; ++j) {
        int x = w0 - 9 + j;
        float2 v = make_float2(0.f, 0.f);
        if ((unsigned)x < (unsigned)W)
          v = *reinterpret_cast<const float2*>(row + 2 * x);
        rx[j] = v.x; ry[j] = v.y;
      }
#pragma unroll
      for (int kx = 0; kx < 7; ++kx) {
        float wa = w_s[ky * 7 + kx];
        float wm = w_s[49 + ky * 7 + kx];
#pragma unroll
        for (int i = 0; i < 4; ++i) {
          acc[i] = fmaf(wa, rx[i + 3 * kx], fmaf(wm, ry[i + 3 * kx], acc[i]));
        }
      }
    }
  }
  st4(att + (size_t)n * (H * W) + hw0,
      make_float4(sigm(acc[0]), sigm(acc[1]), sigm(acc[2]), sigm(acc[3])));
}

__global__ __launch_bounds__(256) void k_conv(float* __restrict__ ws,
                                              const float* __restrict__ cw,
                                              const float* __restrict__ cb) {
  __shared__ float w_s[98];
  unsigned bid = blockIdx.x, tid = threadIdx.x;
  if (tid < 98) w_s[tid] = cw[tid];
  __syncthreads();
  float bias = cb[0];
  if (bid < 512) {
    conv_one<256, 256>(ws + MAP1, ws + ATT1, w_s, bias, bid * 256 + tid);
  } else if (bid < 640) {
    conv_one<128, 128>(ws + MAP2, ws + ATT2, w_s, bias, (bid - 512) * 256 + tid);
  } else if (bid < 672) {
    conv_one<64, 64>(ws + MAP3, ws + ATT3, w_s, bias, (bid - 640) * 256 + tid);
  } else if (bid < 680) {
    conv_one<32, 32>(ws + MAP4, ws + ATT4, w_s, bias, (bid - 672) * 256 + tid);
  } else {
    conv_one<16, 16>(ws + MAP5, ws + ATT5, w_s, bias, (bid - 680) * 256 + tid);
  }
}

// ================= K3: out = t * (1 + att) =================
// Each block: 1024 consecutive quads (thread tid does quads base+tid+j*256).
template <int C, int HW>
DEVINL void apply_four(const float* __restrict__ in, const float* __restrict__ att,
                       float* __restrict__ out, unsigned blockLocal, unsigned tid) {
#pragma unroll
  for (int j = 0; j < 4; ++j) {
    unsigned quad = blockLocal * 1024 + j * 256 + tid;
    size_t e = (size_t)quad * 4;
    unsigned hw0 = (unsigned)(e & (size_t)(HW - 1));
    unsigned n = (unsigned)(e / ((size_t)C * HW));
    float4 a = ld4(att + (size_t)n * HW + hw0);
    float4 t = ld4(in + e);
    st4(out + e, make_float4(fmaf(t.x, a.x, t.x), fmaf(t.y, a.y, t.y),
                             fmaf(t.z, a.z, t.z), fmaf(t.w, a.w, t.w)));
  }
}

// block boundaries (1024-quad units): t1 8192 | t2 4096 | t3 2048 | t4 1024 | t5 256
__global__ __launch_bounds__(256) void k_apply(
    const float* __restrict__ t1, const float* __restrict__ t2,
    const float* __restrict__ t3, const float* __restrict__ t4,
    const float* __restrict__ t5, const float* __restrict__ ws,
    float* __restrict__ out) {
  unsigned bid = blockIdx.x, tid = threadIdx.x;
  if (bid < 8192) {
    apply_four<64, 65536>(t1, ws + ATT1, out + O1, bid, tid);
  } else if (bid < 12288) {
    apply_four<128, 16384>(t2, ws + ATT2, out + O2, bid - 8192, tid);
  } else if (bid < 14336) {
    apply_four<256, 4096>(t3, ws + ATT3, out + O3, bid - 12288, tid);
  } else if (bid < 15360) {
    apply_four<512, 1024>(t4, ws + ATT4, out + O4, bid - 14336, tid);
  } else {
    apply_four<512, 256>(t5, ws + ATT5, out + O5, bid - 15360, tid);
  }
}

extern "C" void kernel_launch(void* const* d_in, const int* in_sizes, int n_in,
                              void* d_out, int out_size, void* d_ws, size_t ws_size,
                              hipStream_t stream) {
  const float* t1 = (const float*)d_in[0];
  const float* t2 = (const float*)d_in[1];
  const float* t3 = (const float*)d_in[2];
  const float* t4 = (const float*)d_in[3];
  const float* t5 = (const float*)d_in[4];
  const float* cw = (const float*)d_in[5];
  const float* cb = (const float*)d_in[6];
  float* out = (float*)d_out;
  float* ws = (float*)d_ws;

  k_reduce<<<752, 256, 0, stream>>>(t1, t2, t3, t4, t5, ws);
  k_conv<<<682, 256, 0, stream>>>(ws, cw, cb);
  k_apply<<<15616, 256, 0, stream>>>(t1, t2, t3, t4, t5, ws, out);
}

// Round 4
// 485.627 us; speedup vs baseline: 1.0367x; 1.0367x over previous
//
#include <hip/hip_runtime.h>
#include <math.h>

#define DEVINL __device__ __forceinline__

typedef float f4 __attribute__((ext_vector_type(4)));

DEVINL float4 ld4(const float* p) { return *reinterpret_cast<const float4*>(p); }
DEVINL void st4(float* p, const float4 v) { *reinterpret_cast<float4*>(p) = v; }
DEVINL f4 ldnt4(const float* p) {
  return __builtin_nontemporal_load(reinterpret_cast<const f4*>(p));
}
DEVINL void stnt4(float* p, f4 v) {
  __builtin_nontemporal_store(v, reinterpret_cast<f4*>(p));
}
DEVINL float sigm(float v) { return 1.0f / (1.0f + expf(-v)); }

// ---------------- shapes ----------------
// t1 (8, 64,256,256)  t2 (8,128,128,128)  t3 (8,256,64,64)
// t4 (8,512, 32, 32)  t5 (8,512, 16, 16)
constexpr size_t O1 = 0;
constexpr size_t O2 = O1 + (size_t)8 * 64 * 256 * 256;
constexpr size_t O3 = O2 + (size_t)8 * 128 * 128 * 128;
constexpr size_t O4 = O3 + (size_t)8 * 256 * 64 * 64;
constexpr size_t O5 = O4 + (size_t)8 * 512 * 32 * 32;

// ws layout (float offsets): interleaved (avg,max) float2 maps, then att maps
constexpr size_t MAP1 = 0;
constexpr size_t MAP2 = MAP1 + (size_t)2 * 8 * 256 * 256;
constexpr size_t MAP3 = MAP2 + (size_t)2 * 8 * 128 * 128;
constexpr size_t MAP4 = MAP3 + (size_t)2 * 8 * 64 * 64;
constexpr size_t MAP5 = MAP4 + (size_t)2 * 8 * 32 * 32;
constexpr size_t ATT1 = MAP5 + (size_t)2 * 8 * 16 * 16;
constexpr size_t ATT2 = ATT1 + (size_t)8 * 256 * 256;
constexpr size_t ATT3 = ATT2 + (size_t)8 * 128 * 128;
constexpr size_t ATT4 = ATT3 + (size_t)8 * 64 * 64;
constexpr size_t ATT5 = ATT4 + (size_t)8 * 32 * 32;

// ================= K1: channel mean+max =================
// t1/t2/t3: 2-way channel split across wave halves, shfl_xor(32) combine.
// Block = 4 waves = 128 quads. Per load instr: two 512B contiguous bursts.
template <int C, int HW>
DEVINL void reduce_shfl(const float* __restrict__ in, float* __restrict__ map,
                        unsigned blockLocal, unsigned tid) {
  constexpr unsigned QPI = HW / 4;  // quads per image
  unsigned wave = tid >> 6;
  unsigned lane = tid & 63;
  unsigned half = lane >> 5;   // 0: channels [0,C/2)  1: [C/2,C)
  unsigned qlane = lane & 31;
  unsigned q = blockLocal * 128 + wave * 32 + qlane;
  unsigned n = q / QPI;
  unsigned hw0 = (q & (QPI - 1)) * 4;
  const float* p = in + (size_t)n * ((size_t)C * HW) +
                   (size_t)(half * (C / 2)) * HW + hw0;
  float sx = 0.f, sy = 0.f, sz = 0.f, sw = 0.f;
  float mx = -3.402823466e38f, my = mx, mz = mx, mw = mx;
#pragma unroll 8
  for (int c = 0; c < C / 2; ++c) {
    float4 v = ld4(p + (size_t)c * HW);
    sx += v.x; sy += v.y; sz += v.z; sw += v.w;
    mx = fmaxf(mx, v.x); my = fmaxf(my, v.y);
    mz = fmaxf(mz, v.z); mw = fmaxf(mw, v.w);
  }
  // combine the two channel halves (lanes l <-> l^32 hold the same quad)
  sx += __shfl_xor(sx, 32); sy += __shfl_xor(sy, 32);
  sz += __shfl_xor(sz, 32); sw += __shfl_xor(sw, 32);
  mx = fmaxf(mx, __shfl_xor(mx, 32)); my = fmaxf(my, __shfl_xor(my, 32));
  mz = fmaxf(mz, __shfl_xor(mz, 32)); mw = fmaxf(mw, __shfl_xor(mw, 32));
  constexpr float inv = 1.0f / C;
  float* mp = map + (size_t)(n * (unsigned)HW + hw0) * 2 + half * 4;
  if (half == 0)
    st4(mp, make_float4(sx * inv, mx, sy * inv, my));
  else
    st4(mp, make_float4(sz * inv, mz, sw * inv, mw));
}

// cooperative version for C=512 tensors: 8 channel-chunks/quad, LDS combine
template <int C, int HW>
DEVINL void reduce_coop(const float* __restrict__ in, float* __restrict__ map,
                        float* s_red, unsigned blockLocal, unsigned tid) {
  constexpr unsigned QPI = HW / 4;
  constexpr int KCH = 8;
  constexpr int CPK = C / KCH;  // 64
  unsigned lane = tid & 31;
  unsigned k = tid >> 5;
  unsigned q = blockLocal * 32 + lane;
  unsigned n = q / QPI;
  unsigned hw0 = (q & (QPI - 1)) * 4;
  const float* p =
      in + (size_t)n * ((size_t)C * HW) + (size_t)(k * CPK) * HW + hw0;
  float sx = 0.f, sy = 0.f, sz = 0.f, sw = 0.f;
  float mx = -3.402823466e38f, my = mx, mz = mx, mw = mx;
#pragma unroll 8
  for (int c = 0; c < CPK; ++c) {
    float4 v = ld4(p + (size_t)c * HW);
    sx += v.x; sy += v.y; sz += v.z; sw += v.w;
    mx = fmaxf(mx, v.x); my = fmaxf(my, v.y);
    mz = fmaxf(mz, v.z); mw = fmaxf(mw, v.w);
  }
  float* slot = s_red + (k * 32 + lane) * 8;
  slot[0] = sx; slot[1] = sy; slot[2] = sz; slot[3] = sw;
  slot[4] = mx; slot[5] = my; slot[6] = mz; slot[7] = mw;
  __syncthreads();
  if (tid < 32) {
    float Sx = 0.f, Sy = 0.f, Sz = 0.f, Sw = 0.f;
    float Mx = -3.402823466e38f, My = Mx, Mz = Mx, Mw = Mx;
#pragma unroll
    for (int j = 0; j < KCH; ++j) {
      const float* sl = s_red + (j * 32 + tid) * 8;
      Sx += sl[0]; Sy += sl[1]; Sz += sl[2]; Sw += sl[3];
      Mx = fmaxf(Mx, sl[4]); My = fmaxf(My, sl[5]);
      Mz = fmaxf(Mz, sl[6]); Mw = fmaxf(Mw, sl[7]);
    }
    unsigned q2 = blockLocal * 32 + tid;
    unsigned n2 = q2 / QPI;
    unsigned hw2 = (q2 & (QPI - 1)) * 4;
    constexpr float inv = 1.0f / C;
    float* mp = map + (size_t)(n2 * (unsigned)HW + hw2) * 2;
    st4(mp,     make_float4(Sx * inv, Mx, Sy * inv, My));
    st4(mp + 4, make_float4(Sz * inv, Mz, Sw * inv, Mw));
  }
}

// grid: t1 [0,1024) t2 [1024,1280) t3 [1280,1344) t4 [1344,1408) t5 [1408,1424)
__global__ __launch_bounds__(256) void k_reduce(
    const float* __restrict__ t1, const float* __restrict__ t2,
    const float* __restrict__ t3, const float* __restrict__ t4,
    const float* __restrict__ t5, float* __restrict__ ws) {
  __shared__ float s_red[8 * 32 * 8];
  unsigned bid = blockIdx.x, tid = threadIdx.x;
  if (bid < 1024) {
    reduce_shfl<64, 65536>(t1, ws + MAP1, bid, tid);
  } else if (bid < 1280) {
    reduce_shfl<128, 16384>(t2, ws + MAP2, bid - 1024, tid);
  } else if (bid < 1344) {
    reduce_shfl<256, 4096>(t3, ws + MAP3, bid - 1280, tid);
  } else if (bid < 1408) {
    reduce_coop<512, 1024>(t4, ws + MAP4, s_red, bid - 1344, tid);
  } else {
    reduce_coop<512, 256>(t5, ws + MAP5, s_red, bid - 1408, tid);
  }
}

// ================= K2: dilated 7x7 conv + sigmoid =================
// cross-correlation, dilation 3, pad 9: y(h,w) = sum in(h+3ky-9, w+3kx-9)*w(ky,kx)
template <int H, int W>
DEVINL void conv_one(const float* __restrict__ map, float* __restrict__ att,
                     const float* w_s, float bias, unsigned quad) {
  constexpr unsigned QPI = (H * W) / 4;
  unsigned n = quad / QPI;
  unsigned hw0 = (quad & (QPI - 1)) * 4;
  int h = (int)(hw0 / (unsigned)W);
  int w0 = (int)(hw0 & (unsigned)(W - 1));
  const float* base = map + (size_t)n * (2 * H * W);
  float acc[4] = {bias, bias, bias, bias};
#pragma unroll
  for (int ky = 0; ky < 7; ++ky) {
    int y = h + (ky - 3) * 3;
    if ((unsigned)y < (unsigned)H) {
      const float* row = base + (size_t)y * (2 * W);
      float rx[22], ry[22];
#pragma unroll
      for (int j = 0; j < 22; ++j) {
        int x = w0 - 9 + j;
        float2 v = make_float2(0.f, 0.f);
        if ((unsigned)x < (unsigned)W)
          v = *reinterpret_cast<const float2*>(row + 2 * x);
        rx[j] = v.x; ry[j] = v.y;
      }
#pragma unroll
      for (int kx = 0; kx < 7; ++kx) {
        float wa = w_s[ky * 7 + kx];
        float wm = w_s[49 + ky * 7 + kx];
#pragma unroll
        for (int i = 0; i < 4; ++i) {
          acc[i] = fmaf(wa, rx[i + 3 * kx], fmaf(wm, ry[i + 3 * kx], acc[i]));
        }
      }
    }
  }
  st4(att + (size_t)n * (H * W) + hw0,
      make_float4(sigm(acc[0]), sigm(acc[1]), sigm(acc[2]), sigm(acc[3])));
}

__global__ __launch_bounds__(256) void k_conv(float* __restrict__ ws,
                                              const float* __restrict__ cw,
                                              const float* __restrict__ cb) {
  __shared__ float w_s[98];
  unsigned bid = blockIdx.x, tid = threadIdx.x;
  if (tid < 98) w_s[tid] = cw[tid];
  __syncthreads();
  float bias = cb[0];
  if (bid < 512) {
    conv_one<256, 256>(ws + MAP1, ws + ATT1, w_s, bias, bid * 256 + tid);
  } else if (bid < 640) {
    conv_one<128, 128>(ws + MAP2, ws + ATT2, w_s, bias, (bid - 512) * 256 + tid);
  } else if (bid < 672) {
    conv_one<64, 64>(ws + MAP3, ws + ATT3, w_s, bias, (bid - 640) * 256 + tid);
  } else if (bid < 680) {
    conv_one<32, 32>(ws + MAP4, ws + ATT4, w_s, bias, (bid - 672) * 256 + tid);
  } else {
    conv_one<16, 16>(ws + MAP5, ws + ATT5, w_s, bias, (bid - 680) * 256 + tid);
  }
}

// ================= K3: out = t * (1 + att) =================
// Block = 2048 consecutive quads; thread does 8 (tid + j*256). NT loads/stores
// for the streamed t/out (touched exactly once); att stays cached.
template <int C, int HW>
DEVINL void apply_eight(const float* __restrict__ in, const float* __restrict__ att,
                        float* __restrict__ out, unsigned blockLocal, unsigned tid) {
#pragma unroll
  for (int j = 0; j < 8; ++j) {
    unsigned quad = blockLocal * 2048 + j * 256 + tid;
    size_t e = (size_t)quad * 4;
    unsigned hw0 = (unsigned)(e & (size_t)(HW - 1));
    unsigned n = (unsigned)(e / ((size_t)C * HW));
    f4 a = *reinterpret_cast<const f4*>(att + (size_t)n * HW + hw0);
    f4 t = ldnt4(in + e);
    f4 r;
    r[0] = fmaf(t[0], a[0], t[0]);
    r[1] = fmaf(t[1], a[1], t[1]);
    r[2] = fmaf(t[2], a[2], t[2]);
    r[3] = fmaf(t[3], a[3], t[3]);
    stnt4(out + e, r);
  }
}

// block boundaries (2048-quad units): t1 4096 | t2 2048 | t3 1024 | t4 512 | t5 128
__global__ __launch_bounds__(256) void k_apply(
    const float* __restrict__ t1, const float* __restrict__ t2,
    const float* __restrict__ t3, const float* __restrict__ t4,
    const float* __restrict__ t5, const float* __restrict__ ws,
    float* __restrict__ out) {
  unsigned bid = blockIdx.x, tid = threadIdx.x;
  if (bid < 4096) {
    apply_eight<64, 65536>(t1, ws + ATT1, out + O1, bid, tid);
  } else if (bid < 6144) {
    apply_eight<128, 16384>(t2, ws + ATT2, out + O2, bid - 4096, tid);
  } else if (bid < 7168) {
    apply_eight<256, 4096>(t3, ws + ATT3, out + O3, bid - 6144, tid);
  } else if (bid < 7680) {
    apply_eight<512, 1024>(t4, ws + ATT4, out + O4, bid - 7168, tid);
  } else {
    apply_eight<512, 256>(t5, ws + ATT5, out + O5, bid - 7680, tid);
  }
}

extern "C" void kernel_launch(void* const* d_in, const int* in_sizes, int n_in,
                              void* d_out, int out_size, void* d_ws, size_t ws_size,
                              hipStream_t stream) {
  const float* t1 = (const float*)d_in[0];
  const float* t2 = (const float*)d_in[1];
  const float* t3 = (const float*)d_in[2];
  const float* t4 = (const float*)d_in[3];
  const float* t5 = (const float*)d_in[4];
  const float* cw = (const float*)d_in[5];
  const float* cb = (const float*)d_in[6];
  float* out = (float*)d_out;
  float* ws = (float*)d_ws;

  k_reduce<<<1424, 256, 0, stream>>>(t1, t2, t3, t4, t5, ws);
  k_conv<<<682, 256, 0, stream>>>(ws, cw, cb);
  k_apply<<<7808, 256, 0, stream>>>(t1, t2, t3, t4, t5, ws, out);
}